// Round 3
// baseline (444.345 us; speedup 1.0000x reference)
//
#include <hip/hip_runtime.h>

typedef __attribute__((ext_vector_type(8))) __bf16 bf16x8;
typedef __attribute__((ext_vector_type(4))) float f32x4;

#define LOG2E 1.4426950408889634f

__device__ __forceinline__ unsigned short f2b(float f) {
  unsigned u = __float_as_uint(f);
  u += 0x7fffu + ((u >> 16) & 1u);   // RNE
  return (unsigned short)(u >> 16);
}
__device__ __forceinline__ float b2f(unsigned short h) {
  return __uint_as_float(((unsigned)h) << 16);
}

// ---------------- 1) x fp32 -> bf16 (row-major [4096][1024]) ----------------
__global__ __launch_bounds__(256) void k_cvt_x(const float* __restrict__ in,
                                               unsigned short* __restrict__ out, int n4) {
  int i = blockIdx.x * blockDim.x + threadIdx.x;
  if (i >= n4) return;
  float4 f = ((const float4*)in)[i];
  ushort4 o;
  o.x = f2b(f.x); o.y = f2b(f.y); o.z = f2b(f.z); o.w = f2b(f.w);
  ((ushort4*)out)[i] = o;
}

// ------- 2) W [1024][2048] fp32 -> Wt [2048][1024] bf16 (transposed) --------
__global__ __launch_bounds__(256) void k_trans_w(const float* __restrict__ W,
                                                 unsigned short* __restrict__ Wt) {
  __shared__ unsigned short tile[64][65];
  int n0 = blockIdx.x * 64;   // over 2048
  int k0 = blockIdx.y * 64;   // over 1024
  int tx = threadIdx.x & 63, ty = threadIdx.x >> 6;
#pragma unroll
  for (int r = 0; r < 16; ++r) {
    int kk = ty * 16 + r;
    tile[kk][tx] = f2b(W[(size_t)(k0 + kk) * 2048 + n0 + tx]);
  }
  __syncthreads();
#pragma unroll
  for (int r = 0; r < 16; ++r) {
    int nn = ty * 16 + r;
    Wt[(size_t)(n0 + nn) * 1024 + k0 + tx] = tile[tx][nn];
  }
}

// ---- 3) GEMM: qk[4096][2048] bf16 = xb[4096][1024] @ Wt[2048][1024]^T ------
// 128x128 block tile, BK=32, 4 waves each 64x64 (4x4 of 16x16x32 MFMA).
__global__ __launch_bounds__(256) void k_gemm_qk(const unsigned short* __restrict__ A,
                                                 const unsigned short* __restrict__ Bt,
                                                 unsigned short* __restrict__ C) {
  __shared__ unsigned short As[128 * 32];
  __shared__ unsigned short Bs[128 * 32];
  const int K = 1024;
  int m0 = blockIdx.x * 128;
  int n0 = blockIdx.y * 128;
  int tid = threadIdx.x;
  int w = tid >> 6, lane = tid & 63;
  int lq = lane & 15, lk8 = (lane >> 4) * 8;
  int wr = (w >> 1) * 64, wc = (w & 1) * 64;
  f32x4 acc[4][4];
#pragma unroll
  for (int i = 0; i < 4; ++i)
#pragma unroll
    for (int j = 0; j < 4; ++j)
#pragma unroll
      for (int r = 0; r < 4; ++r) acc[i][j][r] = 0.f;

  for (int kk = 0; kk < K; kk += 32) {
    bf16x8 sa[2], sb[2];
#pragma unroll
    for (int i = 0; i < 2; ++i) {
      int c = tid + 256 * i;                 // chunk 0..511
      int row = c >> 2, col = (c & 3) * 8;
      sa[i] = *(const bf16x8*)(A + (size_t)(m0 + row) * K + kk + col);
      sb[i] = *(const bf16x8*)(Bt + (size_t)(n0 + row) * K + kk + col);
    }
    __syncthreads();   // previous tile's reads done
#pragma unroll
    for (int i = 0; i < 2; ++i) {
      int c = tid + 256 * i;
      int row = c >> 2, col = (c & 3) * 8;
      *(bf16x8*)(As + row * 32 + col) = sa[i];
      *(bf16x8*)(Bs + row * 32 + col) = sb[i];
    }
    __syncthreads();
    bf16x8 af[4], bf[4];
#pragma unroll
    for (int i = 0; i < 4; ++i) af[i] = *(const bf16x8*)(As + (wr + i * 16 + lq) * 32 + lk8);
#pragma unroll
    for (int j = 0; j < 4; ++j) bf[j] = *(const bf16x8*)(Bs + (wc + j * 16 + lq) * 32 + lk8);
#pragma unroll
    for (int i = 0; i < 4; ++i)
#pragma unroll
      for (int j = 0; j < 4; ++j)
        acc[i][j] = __builtin_amdgcn_mfma_f32_16x16x32_bf16(af[i], bf[j], acc[i][j], 0, 0, 0);
  }
  // epilogue: C/D layout col=lane&15, row=(lane>>4)*4+reg  [m89-verified]
#pragma unroll
  for (int i = 0; i < 4; ++i)
#pragma unroll
    for (int j = 0; j < 4; ++j)
#pragma unroll
      for (int r = 0; r < 4; ++r) {
        int m = m0 + wr + i * 16 + (lane >> 4) * 4 + r;
        int n = n0 + wc + j * 16 + lq;
        C[(size_t)m * 2048 + n] = f2b(acc[i][j][r]);
      }
}

// ------- 4) v[b,t,j,d] = sum_i x[b,t,i*64+d] * v_tmp[i*16+j]  (bf16) --------
__global__ __launch_bounds__(256) void k_vcomp(const float* __restrict__ x,
                                               const float* __restrict__ vt,
                                               unsigned short* __restrict__ vb) {
  __shared__ float s_vt[256];
  s_vt[threadIdx.x] = vt[threadIdx.x];
  __syncthreads();
  int g = blockIdx.x * 256 + threadIdx.x;
  int bt = g >> 6, d = g & 63;
  const float* xp = x + (size_t)bt * 1024 + d;
  float xi[16];
#pragma unroll
  for (int i = 0; i < 16; ++i) xi[i] = xp[i * 64];
#pragma unroll
  for (int j = 0; j < 16; ++j) {
    float s = 0.f;
#pragma unroll
    for (int i = 0; i < 16; ++i) s += xi[i] * s_vt[i * 16 + j];
    vb[(size_t)bt * 1024 + j * 64 + d] = f2b(s);
  }
}

// ------- 5) vb [2][2048][1024] -> Vt [2][1024][2048]  (t-major for PV) ------
__global__ __launch_bounds__(256) void k_vtrans(const unsigned short* __restrict__ vb,
                                                unsigned short* __restrict__ Vt) {
  __shared__ unsigned short tile[64][65];
  int t0 = blockIdx.x * 64;   // 32
  int c0 = blockIdx.y * 64;   // 16
  int b = blockIdx.z;
  int tx = threadIdx.x & 63, ty = threadIdx.x >> 6;
#pragma unroll
  for (int r = 0; r < 16; ++r) {
    int tt = ty * 16 + r;
    tile[tt][tx] = vb[((size_t)b * 2048 + t0 + tt) * 1024 + c0 + tx];
  }
  __syncthreads();
#pragma unroll
  for (int r = 0; r < 16; ++r) {
    int cc = ty * 16 + r;
    Vt[((size_t)b * 1024 + c0 + cc) * 2048 + t0 + tx] = tile[tx][cc];
  }
}

// ---------------- 6) causal flash attention with ALiBi ----------------------
// block = (qtile 64 rows, head, batch); 4 waves x 16 q-rows.
// Q/K/V fragments load straight from global (contraction dims contiguous).
// LDS only for P C-layout -> A-layout round trip (m120-verified pattern).
__global__ __launch_bounds__(256) void k_flash(const unsigned short* __restrict__ qkb, // [2][2048][2048]
                                               const unsigned short* __restrict__ Vt,  // [2][1024][2048]
                                               unsigned short* __restrict__ y) {       // [2][2048][1024]
  __shared__ unsigned short Pbuf[4][16 * 64];
  int qt = blockIdx.x, h = blockIdx.y, b = blockIdx.z;
  int w = threadIdx.x >> 6, lane = threadIdx.x & 63;
  int lq = lane & 15, lk8 = (lane >> 4) * 8;
  int q0 = qt * 64;
  int qg = q0 + w * 16 + lq;                 // A-frag row (m = lane&15)
  const size_t rowb = (size_t)b * 2048;

  bf16x8 qf0 = *(const bf16x8*)(qkb + ((rowb + qg) << 11) + h * 64 + lk8);
  bf16x8 qf1 = *(const bf16x8*)(qkb + ((rowb + qg) << 11) + h * 64 + 32 + lk8);

  float slope = exp2f(-0.5f * (float)(h + 1));   // ALiBi, H=16 power-of-2
  const float c1 = 0.125f * LOG2E;               // 1/sqrt(64) * log2(e)
  const float c2 = slope * LOG2E;

  float m_r[4], l_r[4];
  f32x4 o[4];
#pragma unroll
  for (int r = 0; r < 4; ++r) { m_r[r] = -1e30f; l_r[r] = 0.f; }
#pragma unroll
  for (int j = 0; j < 4; ++j)
#pragma unroll
    for (int r = 0; r < 4; ++r) o[j][r] = 0.f;

  int qrow_base = q0 + w * 16 + (lane >> 4) * 4;  // C-layout row + r

  for (int kt = 0; kt <= qt; ++kt) {   // diagonal tile == last tile for every wave
    int k0 = kt * 64;
    f32x4 S[4];
#pragma unroll
    for (int s = 0; s < 4; ++s) {
      const unsigned short* kp = qkb + ((rowb + k0 + s * 16 + lq) << 11) + 1024 + h * 64;
      bf16x8 kf0 = *(const bf16x8*)(kp + lk8);
      bf16x8 kf1 = *(const bf16x8*)(kp + 32 + lk8);
      f32x4 a;
#pragma unroll
      for (int r = 0; r < 4; ++r) a[r] = 0.f;
      a = __builtin_amdgcn_mfma_f32_16x16x32_bf16(qf0, kf0, a, 0, 0, 0);
      a = __builtin_amdgcn_mfma_f32_16x16x32_bf16(qf1, kf1, a, 0, 0, 0);
      S[s] = a;
    }
    float mx[4] = {-1e30f, -1e30f, -1e30f, -1e30f};
    float p[4][4];
#pragma unroll
    for (int s = 0; s < 4; ++s) {
      int kg = k0 + s * 16 + lq;
#pragma unroll
      for (int r = 0; r < 4; ++r) {
        int qr = qrow_base + r;
        float v = S[s][r] * c1 + c2 * (float)(kg - qr);
        v = (kg <= qr) ? v : -1e30f;
        p[s][r] = v;
        mx[r] = fmaxf(mx[r], v);
      }
    }
#pragma unroll
    for (int r = 0; r < 4; ++r) {
      mx[r] = fmaxf(mx[r], __shfl_xor(mx[r], 1, 64));
      mx[r] = fmaxf(mx[r], __shfl_xor(mx[r], 2, 64));
      mx[r] = fmaxf(mx[r], __shfl_xor(mx[r], 4, 64));
      mx[r] = fmaxf(mx[r], __shfl_xor(mx[r], 8, 64));
    }
    float alpha[4], tsum[4];
#pragma unroll
    for (int r = 0; r < 4; ++r) {
      float mn = fmaxf(m_r[r], mx[r]);
      alpha[r] = exp2f(m_r[r] - mn);
      m_r[r] = mn;
      tsum[r] = 0.f;
    }
#pragma unroll
    for (int s = 0; s < 4; ++s)
#pragma unroll
      for (int r = 0; r < 4; ++r) {
        float e = exp2f(p[s][r] - m_r[r]);
        p[s][r] = e;
        tsum[r] += e;
      }
#pragma unroll
    for (int r = 0; r < 4; ++r) {
      tsum[r] += __shfl_xor(tsum[r], 1, 64);
      tsum[r] += __shfl_xor(tsum[r], 2, 64);
      tsum[r] += __shfl_xor(tsum[r], 4, 64);
      tsum[r] += __shfl_xor(tsum[r], 8, 64);
      l_r[r] = l_r[r] * alpha[r] + tsum[r];
    }
#pragma unroll
    for (int j = 0; j < 4; ++j)
#pragma unroll
      for (int r = 0; r < 4; ++r) o[j][r] *= alpha[r];
    // P: C-layout (col=lane&15,row=quad*4+r) -> LDS -> A-layout (m=lane&15,k=quad*8+j)
#pragma unroll
    for (int s = 0; s < 4; ++s)
#pragma unroll
      for (int r = 0; r < 4; ++r)
        Pbuf[w][((lane >> 4) * 4 + r) * 64 + s * 16 + lq] = f2b(p[s][r]);
    bf16x8 pf0 = *(const bf16x8*)(&Pbuf[w][lq * 64 + lk8]);
    bf16x8 pf1 = *(const bf16x8*)(&Pbuf[w][lq * 64 + 32 + lk8]);
#pragma unroll
    for (int j = 0; j < 4; ++j) {
      const unsigned short* vp = Vt + ((size_t)b * 1024 + h * 64 + j * 16 + lq) * 2048 + k0;
      bf16x8 vf0 = *(const bf16x8*)(vp + lk8);
      bf16x8 vf1 = *(const bf16x8*)(vp + 32 + lk8);
      o[j] = __builtin_amdgcn_mfma_f32_16x16x32_bf16(pf0, vf0, o[j], 0, 0, 0);
      o[j] = __builtin_amdgcn_mfma_f32_16x16x32_bf16(pf1, vf1, o[j], 0, 0, 0);
    }
  }
#pragma unroll
  for (int r = 0; r < 4; ++r) {
    float inv = 1.0f / l_r[r];
    int qr = qrow_base + r;
#pragma unroll
    for (int j = 0; j < 4; ++j)
      y[((rowb + qr) << 10) + h * 64 + j * 16 + lq] = f2b(o[j][r] * inv);
  }
}

// --- 7) out[b,t,i*64+d] = sum_j y[b,t,j*64+d] * proj_tmp[i*16+j]  (FP32 out) ---
__global__ __launch_bounds__(256) void k_proj(const unsigned short* __restrict__ yb,
                                              const float* __restrict__ pt,
                                              float* __restrict__ out) {
  __shared__ float s_pt[256];
  s_pt[threadIdx.x] = pt[threadIdx.x];
  __syncthreads();
  int g = blockIdx.x * 256 + threadIdx.x;
  int bt = g >> 6, d = g & 63;
  float yj[16];
#pragma unroll
  for (int j = 0; j < 16; ++j) yj[j] = b2f(yb[(size_t)bt * 1024 + j * 64 + d]);
#pragma unroll
  for (int i = 0; i < 16; ++i) {
    float s = 0.f;
#pragma unroll
    for (int j = 0; j < 16; ++j) s += yj[j] * s_pt[i * 16 + j];
    out[(size_t)bt * 1024 + i * 64 + d] = s;   // fp32 output (round-2 analysis)
  }
}

extern "C" void kernel_launch(void* const* d_in, const int* in_sizes, int n_in,
                              void* d_out, int out_size, void* d_ws, size_t ws_size,
                              hipStream_t stream) {
  // Inputs fp32 (NaN experiment, round 2); output fp32 (R1 aliasing signature).
  const float* x  = (const float*)d_in[0];   // [2][2048][1024] fp32
  const float* W  = (const float*)d_in[1];   // [1024][2048] fp32
  const float* vt = (const float*)d_in[2];   // [16][16] fp32
  const float* pt = (const float*)d_in[3];   // [16][16] fp32
  float* out = (float*)d_out;                // fp32 out

  char* ws = (char*)d_ws;
  unsigned short* xb  = (unsigned short*)(ws);                 //  8 MiB, reused as y
  unsigned short* Wt  = (unsigned short*)(ws + (8u  << 20));   //  4 MiB
  unsigned short* qkb = (unsigned short*)(ws + (12u << 20));   // 16 MiB
  unsigned short* vb  = (unsigned short*)(ws + (28u << 20));   //  8 MiB
  unsigned short* Vtr = (unsigned short*)(ws + (36u << 20));   //  8 MiB
  unsigned short* yb  = xb;  // xb dead after GEMM; flash writes y there

  k_cvt_x  <<<4096, 256, 0, stream>>>(x, xb, 4194304 / 4);
  k_trans_w<<<dim3(32, 16), 256, 0, stream>>>(W, Wt);
  k_gemm_qk<<<dim3(32, 16), 256, 0, stream>>>(xb, Wt, qkb);
  k_vcomp  <<<1024, 256, 0, stream>>>(x, vt, vb);
  k_vtrans <<<dim3(32, 16, 2), 256, 0, stream>>>(vb, Vtr);
  k_flash  <<<dim3(32, 16, 2), 256, 0, stream>>>(qkb, Vtr, yb);
  k_proj   <<<1024, 256, 0, stream>>>(yb, pt, out);
}

// Round 4
// 247.337 us; speedup vs baseline: 1.7965x; 1.7965x over previous
//
#include <hip/hip_runtime.h>

typedef __attribute__((ext_vector_type(8))) __bf16 bf16x8;
typedef __attribute__((ext_vector_type(4))) float f32x4;

#define LOG2E 1.4426950408889634f

__device__ __forceinline__ unsigned short f2b(float f) {
  unsigned u = __float_as_uint(f);
  u += 0x7fffu + ((u >> 16) & 1u);   // RNE
  return (unsigned short)(u >> 16);
}
__device__ __forceinline__ float b2f(unsigned short h) {
  return __uint_as_float(((unsigned)h) << 16);
}

// ---------------- 1) x fp32 -> bf16 (row-major [4096][1024]) ----------------
__global__ __launch_bounds__(256) void k_cvt_x(const float* __restrict__ in,
                                               unsigned short* __restrict__ out, int n4) {
  int i = blockIdx.x * blockDim.x + threadIdx.x;
  if (i >= n4) return;
  float4 f = ((const float4*)in)[i];
  ushort4 o;
  o.x = f2b(f.x); o.y = f2b(f.y); o.z = f2b(f.z); o.w = f2b(f.w);
  ((ushort4*)out)[i] = o;
}

// ------- 2) W [1024][2048] fp32 -> Wt [2048][1024] bf16 (transposed) --------
__global__ __launch_bounds__(256) void k_trans_w(const float* __restrict__ W,
                                                 unsigned short* __restrict__ Wt) {
  __shared__ unsigned short tile[64][65];
  int n0 = blockIdx.x * 64;   // over 2048
  int k0 = blockIdx.y * 64;   // over 1024
  int tx = threadIdx.x & 63, ty = threadIdx.x >> 6;
#pragma unroll
  for (int r = 0; r < 16; ++r) {
    int kk = ty * 16 + r;
    tile[kk][tx] = f2b(W[(size_t)(k0 + kk) * 2048 + n0 + tx]);
  }
  __syncthreads();
#pragma unroll
  for (int r = 0; r < 16; ++r) {
    int nn = ty * 16 + r;
    Wt[(size_t)(n0 + nn) * 1024 + k0 + tx] = tile[tx][nn];
  }
}

// ---- 3) GEMM: qk[4096][2048] bf16 = xb[4096][1024] @ Wt[2048][1024]^T ------
__global__ __launch_bounds__(256) void k_gemm_qk(const unsigned short* __restrict__ A,
                                                 const unsigned short* __restrict__ Bt,
                                                 unsigned short* __restrict__ C) {
  __shared__ unsigned short As[128 * 32];
  __shared__ unsigned short Bs[128 * 32];
  const int K = 1024;
  int m0 = blockIdx.x * 128;
  int n0 = blockIdx.y * 128;
  int tid = threadIdx.x;
  int w = tid >> 6, lane = tid & 63;
  int lq = lane & 15, lk8 = (lane >> 4) * 8;
  int wr = (w >> 1) * 64, wc = (w & 1) * 64;
  f32x4 acc[4][4];
#pragma unroll
  for (int i = 0; i < 4; ++i)
#pragma unroll
    for (int j = 0; j < 4; ++j)
#pragma unroll
      for (int r = 0; r < 4; ++r) acc[i][j][r] = 0.f;

  for (int kk = 0; kk < K; kk += 32) {
    bf16x8 sa[2], sb[2];
#pragma unroll
    for (int i = 0; i < 2; ++i) {
      int c = tid + 256 * i;
      int row = c >> 2, col = (c & 3) * 8;
      sa[i] = *(const bf16x8*)(A + (size_t)(m0 + row) * K + kk + col);
      sb[i] = *(const bf16x8*)(Bt + (size_t)(n0 + row) * K + kk + col);
    }
    __syncthreads();
#pragma unroll
    for (int i = 0; i < 2; ++i) {
      int c = tid + 256 * i;
      int row = c >> 2, col = (c & 3) * 8;
      *(bf16x8*)(As + row * 32 + col) = sa[i];
      *(bf16x8*)(Bs + row * 32 + col) = sb[i];
    }
    __syncthreads();
    bf16x8 af[4], bf[4];
#pragma unroll
    for (int i = 0; i < 4; ++i) af[i] = *(const bf16x8*)(As + (wr + i * 16 + lq) * 32 + lk8);
#pragma unroll
    for (int j = 0; j < 4; ++j) bf[j] = *(const bf16x8*)(Bs + (wc + j * 16 + lq) * 32 + lk8);
#pragma unroll
    for (int i = 0; i < 4; ++i)
#pragma unroll
      for (int j = 0; j < 4; ++j)
        acc[i][j] = __builtin_amdgcn_mfma_f32_16x16x32_bf16(af[i], bf[j], acc[i][j], 0, 0, 0);
  }
#pragma unroll
  for (int i = 0; i < 4; ++i)
#pragma unroll
    for (int j = 0; j < 4; ++j)
#pragma unroll
      for (int r = 0; r < 4; ++r) {
        int m = m0 + wr + i * 16 + (lane >> 4) * 4 + r;
        int n = n0 + wc + j * 16 + lq;
        C[(size_t)m * 2048 + n] = f2b(acc[i][j][r]);
      }
}

// ------- 4) v[b,t,j,d] = sum_i x[b,t,i*64+d] * v_tmp[i*16+j]  (bf16) --------
__global__ __launch_bounds__(256) void k_vcomp(const float* __restrict__ x,
                                               const float* __restrict__ vt,
                                               unsigned short* __restrict__ vb) {
  __shared__ float s_vt[256];
  s_vt[threadIdx.x] = vt[threadIdx.x];
  __syncthreads();
  int g = blockIdx.x * 256 + threadIdx.x;
  int bt = g >> 6, d = g & 63;
  const float* xp = x + (size_t)bt * 1024 + d;
  float xi[16];
#pragma unroll
  for (int i = 0; i < 16; ++i) xi[i] = xp[i * 64];
#pragma unroll
  for (int j = 0; j < 16; ++j) {
    float s = 0.f;
#pragma unroll
    for (int i = 0; i < 16; ++i) s += xi[i] * s_vt[i * 16 + j];
    vb[(size_t)bt * 1024 + j * 64 + d] = f2b(s);
  }
}

// ------- 5) vb [2][2048][1024] -> Vt [2][1024][2048]  (t-major for PV) ------
__global__ __launch_bounds__(256) void k_vtrans(const unsigned short* __restrict__ vb,
                                                unsigned short* __restrict__ Vt) {
  __shared__ unsigned short tile[64][65];
  int t0 = blockIdx.x * 64;
  int c0 = blockIdx.y * 64;
  int b = blockIdx.z;
  int tx = threadIdx.x & 63, ty = threadIdx.x >> 6;
#pragma unroll
  for (int r = 0; r < 16; ++r) {
    int tt = ty * 16 + r;
    tile[tt][tx] = vb[((size_t)b * 2048 + t0 + tt) * 1024 + c0 + tx];
  }
  __syncthreads();
#pragma unroll
  for (int r = 0; r < 16; ++r) {
    int cc = ty * 16 + r;
    Vt[((size_t)b * 1024 + c0 + cc) * 2048 + t0 + tx] = tile[tx][cc];
  }
}

// ---------------- 6) causal flash attention with ALiBi ----------------------
// R4: paired q-tiles {bx, 31-bx} per block (perfect balance: 33 tiles each);
// K-register prefetch pipeline + early V issue (softmax covers load latency).
__global__ __launch_bounds__(256) void k_flash(const unsigned short* __restrict__ qkb, // [2][2048][2048]
                                               const unsigned short* __restrict__ Vt,  // [2][1024][2048]
                                               unsigned short* __restrict__ y) {       // [2][2048][1024]
  __shared__ unsigned short Pbuf[4][16 * 64];
  int h = blockIdx.y, b = blockIdx.z;
  int w = threadIdx.x >> 6, lane = threadIdx.x & 63;
  int lq = lane & 15, lk8 = (lane >> 4) * 8;
  const size_t rowb = (size_t)b * 2048;

  float slope = exp2f(-0.5f * (float)(h + 1));   // ALiBi, H=16 power-of-2
  const float c1 = 0.125f * LOG2E;               // 1/sqrt(64) * log2(e)
  const float c2 = slope * LOG2E;

#pragma unroll 1
  for (int pass = 0; pass < 2; ++pass) {
    int qt = pass ? (31 - (int)blockIdx.x) : (int)blockIdx.x;
    int q0 = qt * 64;
    int qg = q0 + w * 16 + lq;                 // A-frag row (m = lane&15)

    bf16x8 qf0 = *(const bf16x8*)(qkb + ((rowb + qg) << 11) + h * 64 + lk8);
    bf16x8 qf1 = *(const bf16x8*)(qkb + ((rowb + qg) << 11) + h * 64 + 32 + lk8);

    float m_r[4], l_r[4];
    f32x4 o[4];
#pragma unroll
    for (int r = 0; r < 4; ++r) { m_r[r] = -1e30f; l_r[r] = 0.f; }
#pragma unroll
    for (int j = 0; j < 4; ++j)
#pragma unroll
      for (int r = 0; r < 4; ++r) o[j][r] = 0.f;

    int qrow_base = q0 + w * 16 + (lane >> 4) * 4;  // C-layout row + r

    // K prologue: tile 0 into registers
    bf16x8 kc[4][2];
#pragma unroll
    for (int s = 0; s < 4; ++s) {
      const unsigned short* kp = qkb + ((rowb + s * 16 + lq) << 11) + 1024 + h * 64;
      kc[s][0] = *(const bf16x8*)(kp + lk8);
      kc[s][1] = *(const bf16x8*)(kp + 32 + lk8);
    }

#pragma unroll 1
    for (int kt = 0; kt <= qt; ++kt) {
      int k0 = kt * 64;
      // early-issue V(kt) — consumed after softmax
      bf16x8 vc[4][2];
#pragma unroll
      for (int j = 0; j < 4; ++j) {
        const unsigned short* vp = Vt + ((size_t)b * 1024 + h * 64 + j * 16 + lq) * 2048 + k0;
        vc[j][0] = *(const bf16x8*)(vp + lk8);
        vc[j][1] = *(const bf16x8*)(vp + 32 + lk8);
      }
      // prefetch K(kt+1) — consumed next iteration
      int k0n = (kt < qt) ? k0 + 64 : k0;
      bf16x8 kn[4][2];
#pragma unroll
      for (int s = 0; s < 4; ++s) {
        const unsigned short* kp = qkb + ((rowb + k0n + s * 16 + lq) << 11) + 1024 + h * 64;
        kn[s][0] = *(const bf16x8*)(kp + lk8);
        kn[s][1] = *(const bf16x8*)(kp + 32 + lk8);
      }
      // QK^T with current K registers
      f32x4 S[4];
#pragma unroll
      for (int s = 0; s < 4; ++s) {
        f32x4 a;
#pragma unroll
        for (int r = 0; r < 4; ++r) a[r] = 0.f;
        a = __builtin_amdgcn_mfma_f32_16x16x32_bf16(qf0, kc[s][0], a, 0, 0, 0);
        a = __builtin_amdgcn_mfma_f32_16x16x32_bf16(qf1, kc[s][1], a, 0, 0, 0);
        S[s] = a;
      }
      float mx[4] = {-1e30f, -1e30f, -1e30f, -1e30f};
      float p[4][4];
#pragma unroll
      for (int s = 0; s < 4; ++s) {
        int kg = k0 + s * 16 + lq;
#pragma unroll
        for (int r = 0; r < 4; ++r) {
          int qr = qrow_base + r;
          float v = S[s][r] * c1 + c2 * (float)(kg - qr);
          v = (kg <= qr) ? v : -1e30f;
          p[s][r] = v;
          mx[r] = fmaxf(mx[r], v);
        }
      }
#pragma unroll
      for (int r = 0; r < 4; ++r) {
        mx[r] = fmaxf(mx[r], __shfl_xor(mx[r], 1, 64));
        mx[r] = fmaxf(mx[r], __shfl_xor(mx[r], 2, 64));
        mx[r] = fmaxf(mx[r], __shfl_xor(mx[r], 4, 64));
        mx[r] = fmaxf(mx[r], __shfl_xor(mx[r], 8, 64));
      }
      float alpha[4], tsum[4];
#pragma unroll
      for (int r = 0; r < 4; ++r) {
        float mn = fmaxf(m_r[r], mx[r]);
        alpha[r] = exp2f(m_r[r] - mn);
        m_r[r] = mn;
        tsum[r] = 0.f;
      }
#pragma unroll
      for (int s = 0; s < 4; ++s)
#pragma unroll
        for (int r = 0; r < 4; ++r) {
          float e = exp2f(p[s][r] - m_r[r]);
          p[s][r] = e;
          tsum[r] += e;
        }
#pragma unroll
      for (int r = 0; r < 4; ++r) {
        tsum[r] += __shfl_xor(tsum[r], 1, 64);
        tsum[r] += __shfl_xor(tsum[r], 2, 64);
        tsum[r] += __shfl_xor(tsum[r], 4, 64);
        tsum[r] += __shfl_xor(tsum[r], 8, 64);
        l_r[r] = l_r[r] * alpha[r] + tsum[r];
      }
#pragma unroll
      for (int j = 0; j < 4; ++j)
#pragma unroll
        for (int r = 0; r < 4; ++r) o[j][r] *= alpha[r];
      // P: C-layout -> LDS -> A-layout (per-wave buffer, no barrier needed)
#pragma unroll
      for (int s = 0; s < 4; ++s)
#pragma unroll
        for (int r = 0; r < 4; ++r)
          Pbuf[w][((lane >> 4) * 4 + r) * 64 + s * 16 + lq] = f2b(p[s][r]);
      bf16x8 pf0 = *(const bf16x8*)(&Pbuf[w][lq * 64 + lk8]);
      bf16x8 pf1 = *(const bf16x8*)(&Pbuf[w][lq * 64 + 32 + lk8]);
#pragma unroll
      for (int j = 0; j < 4; ++j) {
        o[j] = __builtin_amdgcn_mfma_f32_16x16x32_bf16(pf0, vc[j][0], o[j], 0, 0, 0);
        o[j] = __builtin_amdgcn_mfma_f32_16x16x32_bf16(pf1, vc[j][1], o[j], 0, 0, 0);
      }
      // advance K pipeline
#pragma unroll
      for (int s = 0; s < 4; ++s) { kc[s][0] = kn[s][0]; kc[s][1] = kn[s][1]; }
    }
#pragma unroll
    for (int r = 0; r < 4; ++r) {
      float inv = 1.0f / l_r[r];
      int qr = qrow_base + r;
#pragma unroll
      for (int j = 0; j < 4; ++j)
        y[((rowb + qr) << 10) + h * 64 + j * 16 + lq] = f2b(o[j][r] * inv);
    }
  }
}

// --- 7) out[b,t,i*64+d] = sum_j y[b,t,j*64+d] * proj_tmp[i*16+j]  (FP32 out) ---
__global__ __launch_bounds__(256) void k_proj(const unsigned short* __restrict__ yb,
                                              const float* __restrict__ pt,
                                              float* __restrict__ out) {
  __shared__ float s_pt[256];
  s_pt[threadIdx.x] = pt[threadIdx.x];
  __syncthreads();
  int g = blockIdx.x * 256 + threadIdx.x;
  int bt = g >> 6, d = g & 63;
  float yj[16];
#pragma unroll
  for (int j = 0; j < 16; ++j) yj[j] = b2f(yb[(size_t)bt * 1024 + j * 64 + d]);
#pragma unroll
  for (int i = 0; i < 16; ++i) {
    float s = 0.f;
#pragma unroll
    for (int j = 0; j < 16; ++j) s += yj[j] * s_pt[i * 16 + j];
    out[(size_t)bt * 1024 + i * 64 + d] = s;
  }
}

extern "C" void kernel_launch(void* const* d_in, const int* in_sizes, int n_in,
                              void* d_out, int out_size, void* d_ws, size_t ws_size,
                              hipStream_t stream) {
  const float* x  = (const float*)d_in[0];   // [2][2048][1024] fp32
  const float* W  = (const float*)d_in[1];   // [1024][2048] fp32
  const float* vt = (const float*)d_in[2];   // [16][16] fp32
  const float* pt = (const float*)d_in[3];   // [16][16] fp32
  float* out = (float*)d_out;                // fp32 out

  char* ws = (char*)d_ws;
  unsigned short* xb  = (unsigned short*)(ws);                 //  8 MiB, reused as y
  unsigned short* Wt  = (unsigned short*)(ws + (8u  << 20));   //  4 MiB
  unsigned short* qkb = (unsigned short*)(ws + (12u << 20));   // 16 MiB
  unsigned short* vb  = (unsigned short*)(ws + (28u << 20));   //  8 MiB
  unsigned short* Vtr = (unsigned short*)(ws + (36u << 20));   //  8 MiB
  unsigned short* yb  = xb;  // xb dead after GEMM; flash writes y there

  k_cvt_x  <<<4096, 256, 0, stream>>>(x, xb, 4194304 / 4);
  k_trans_w<<<dim3(32, 16), 256, 0, stream>>>(W, Wt);
  k_gemm_qk<<<dim3(32, 16), 256, 0, stream>>>(xb, Wt, qkb);
  k_vcomp  <<<1024, 256, 0, stream>>>(x, vt, vb);
  k_vtrans <<<dim3(32, 16, 2), 256, 0, stream>>>(vb, Vtr);
  k_flash  <<<dim3(16, 16, 2), 256, 0, stream>>>(qkb, Vtr, yb);
  k_proj   <<<1024, 256, 0, stream>>>(yb, pt, out);
}